// Round 4
// baseline (88.569 us; speedup 1.0000x reference)
//
#include <hip/hip_runtime.h>

#define OUTS 7
#define CC 256
#define HH 56
#define WW 56
#define PX (HH * WW)   // 3136
#define STRIDE8 57     // uint4 pixels per LDS row (odd: spreads banks)
#define SPLIT 2        // ROI-list split across sibling blocks
#define MAXROI 96

typedef _Float16 half2_t __attribute__((ext_vector_type(2)));  // trivially copyable

__device__ __forceinline__ unsigned packh2(float a, float b) {
    half2_t h = { (_Float16)a, (_Float16)b };
    return __builtin_bit_cast(unsigned, h);
}

// R14: exact-bounds scan. R13 (-1.1us for halving scan reads) proved the
// scan phase is on the critical path at ~2-3us. The 2x2 clamped chunking
// over-reads ~1.8x on the typical ~3x3-px bin (ceil-to-even in both dims).
// Since an ROI's 49 bins partition its crop, exact bounds read each crop
// pixel exactly once -- the minimum. Exact row iteration + x-pairs with a
// single tail read: per-ROI wave-wide ds_read_b128 ~16 -> 9. Everything
// else (8-ch uint4 plane, SPLIT=2, deterministic list) unchanged.
// Pre-commit: gain < 0.8us => harness floor reached, ROOFLINE next round.
__global__ __launch_bounds__(256) void roipool_kernel(
    const float* __restrict__ images, const float* __restrict__ rois,
    const int* __restrict__ roi_idx, float* __restrict__ out, int R)
{
    __shared__ __align__(16) uint4 plane[STRIDE8 * HH];  // 51072 B
    __shared__ int    list[MAXROI];
    __shared__ unsigned short ys[MAXROI * 7];   // sy | ey<<8
    __shared__ unsigned short xs[MAXROI * 7];   // sx | ex<<8
    __shared__ int cnt;

    const int b  = blockIdx.x;
    const int s  = b & (SPLIT - 1);
    const int pq = b >> 1;             // n*32 + c-octet
    const int n  = pq >> 5;
    const int c0 = (pq & 31) * 8;
    const int t  = threadIdx.x;

    // Deterministic ascending-r compaction (wave 0 only) -- identical list
    // order across sibling blocks (R4 lesson: atomicAdd order is not).
    if (t < 64) {
        int base = 0;
        #pragma unroll
        for (int k = 0; k < 4; ++k) {
            int r = k * 64 + t;
            bool match = (r < R) && (roi_idx[r] == n);
            unsigned long long mask = __ballot(match);
            int pos = base + __popcll(mask & ((1ULL << t) - 1ULL));
            if (match && pos < MAXROI) list[pos] = r;
            base += __popcll(mask);
        }
        if (t == 0) cnt = (base < MAXROI) ? base : MAXROI;
    }

    // Stage 8 planes packed-fp16: plane[y*57+x] = {h2(c0,c1),h2(c2,c3),
    // h2(c4,c5),h2(c6,c7)}. 784 pixel-quads, 14 quads/row -> no row spans.
    const float* base8 = images + (size_t)(n * CC + c0) * PX;
    #pragma unroll
    for (int k = 0; k < 4; ++k) {
        int idx = t + k * 256;
        if (idx < PX / 4) {
            float4 v[8];
            #pragma unroll
            for (int p = 0; p < 8; ++p)
                v[p] = reinterpret_cast<const float4*>(base8 + (size_t)p * PX)[idx];
            int y  = idx / 14;
            int x0 = (idx - y * 14) * 4;
            uint4* dst = &plane[y * STRIDE8 + x0];
            #pragma unroll
            for (int q = 0; q < 4; ++q) {
                const float f0 = ((const float*)&v[0])[q];
                const float f1 = ((const float*)&v[1])[q];
                const float f2 = ((const float*)&v[2])[q];
                const float f3 = ((const float*)&v[3])[q];
                const float f4 = ((const float*)&v[4])[q];
                const float f5 = ((const float*)&v[5])[q];
                const float f6 = ((const float*)&v[6])[q];
                const float f7 = ((const float*)&v[7])[q];
                dst[q] = make_uint4(packh2(f0, f1), packh2(f2, f3),
                                    packh2(f4, f5), packh2(f6, f7));
            }
        }
    }
    __syncthreads();   // covers list/cnt too

    const int count = cnt;

    // Per-ROI bin-edge tables (e = m*7 + i serves rows and cols).
    for (int e = t; e < count * 7; e += 256) {
        int m = e / 7, i = e - m * 7;
        int r = list[m];
        float4 rv = reinterpret_cast<const float4*>(rois)[r];
        int x1 = (int)floorf(rv.x * (float)WW);
        int y1 = (int)floorf(rv.y * (float)HH);
        int x2 = (int)ceilf (rv.z * (float)WW);
        int y2 = (int)ceilf (rv.w * (float)HH);
        int Hr = y2 - y1, Wr = x2 - x1;
        int sy = y1 + (i * Hr) / 7, ey = y1 + ((i + 1) * Hr + 6) / 7;
        int sx = x1 + (i * Wr) / 7, ex = x1 + ((i + 1) * Wr + 6) / 7;
        ys[m * 7 + i] = (unsigned short)(sy | (ey << 8));
        xs[m * 7 + i] = (unsigned short)(sx | (ex << 8));
    }
    __syncthreads();

    const int wv   = t >> 6;
    const int lane = t & 63;
    const int i = lane / 7;
    const int j = lane - i * 7;

    if (lane < OUTS * OUTS) {
        const half2_t NEG = { (_Float16)-65504.0f, (_Float16)-65504.0f };
        // (chunk s, wave wv) takes list positions m % 8 == s + 2*wv.
        for (int m = (wv << 1) + s; m < count; m += SPLIT * 4) {
            int r = list[m];
            int yse = ys[m * 7 + i];
            int xse = xs[m * 7 + j];
            int sy = yse & 255, ey = yse >> 8;
            int sx = xse & 255, ex = xse >> 8;

            half2_t a01 = NEG, a23 = NEG, a45 = NEG, a67 = NEG;

            // Exact-bounds scan: each crop pixel read exactly once. x-pairs
            // give 2 independent ds_read_b128 of ILP; odd widths take one
            // tail read. No clamp duplicates.
            for (int y = sy; y < ey; ++y) {
                const uint4* row = plane + y * STRIDE8;
                int x = sx;
                for (; x + 2 <= ex; x += 2) {
                    uint4 v0 = row[x], v1 = row[x + 1];
                    a01 = __builtin_elementwise_max(a01, __builtin_bit_cast(half2_t, v0.x));
                    a23 = __builtin_elementwise_max(a23, __builtin_bit_cast(half2_t, v0.y));
                    a45 = __builtin_elementwise_max(a45, __builtin_bit_cast(half2_t, v0.z));
                    a67 = __builtin_elementwise_max(a67, __builtin_bit_cast(half2_t, v0.w));
                    a01 = __builtin_elementwise_max(a01, __builtin_bit_cast(half2_t, v1.x));
                    a23 = __builtin_elementwise_max(a23, __builtin_bit_cast(half2_t, v1.y));
                    a45 = __builtin_elementwise_max(a45, __builtin_bit_cast(half2_t, v1.z));
                    a67 = __builtin_elementwise_max(a67, __builtin_bit_cast(half2_t, v1.w));
                }
                if (x < ex) {
                    uint4 v0 = row[x];
                    a01 = __builtin_elementwise_max(a01, __builtin_bit_cast(half2_t, v0.x));
                    a23 = __builtin_elementwise_max(a23, __builtin_bit_cast(half2_t, v0.y));
                    a45 = __builtin_elementwise_max(a45, __builtin_bit_cast(half2_t, v0.z));
                    a67 = __builtin_elementwise_max(a67, __builtin_bit_cast(half2_t, v0.w));
                }
            }

            // Unpack fp16 -> f32. Degenerate bins (Wr*Hr==0 edge case) get
            // exact finfo(f32).min to match the reference.
            bool ok = (ey > sy) && (ex > sx);
            const float NF = -3.402823466e+38f;
            float f0 = ok ? (float)a01.x : NF;
            float f1 = ok ? (float)a01.y : NF;
            float f2 = ok ? (float)a23.x : NF;
            float f3 = ok ? (float)a23.y : NF;
            float f4 = ok ? (float)a45.x : NF;
            float f5 = ok ? (float)a45.y : NF;
            float f6 = ok ? (float)a67.x : NF;
            float f7 = ok ? (float)a67.y : NF;

            size_t o = ((size_t)r * CC + c0) * (OUTS * OUTS) + lane;
            out[o]            = f0;
            out[o + 49]       = f1;
            out[o + 49 * 2]   = f2;
            out[o + 49 * 3]   = f3;
            out[o + 49 * 4]   = f4;
            out[o + 49 * 5]   = f5;
            out[o + 49 * 6]   = f6;
            out[o + 49 * 7]   = f7;
        }
    }
}

extern "C" void kernel_launch(void* const* d_in, const int* in_sizes, int n_in,
                              void* d_out, int out_size, void* d_ws, size_t ws_size,
                              hipStream_t stream) {
    const float* images  = (const float*)d_in[0];
    const float* rois    = (const float*)d_in[1];
    const int*   roi_idx = (const int*)d_in[2];
    float* out = (float*)d_out;

    int R = in_sizes[2];                         // 256
    int N = in_sizes[0] / (CC * PX);             // 8

    int grid = N * (CC / 8) * SPLIT;             // 512 blocks
    roipool_kernel<<<grid, 256, 0, stream>>>(images, rois, roi_idx, out, R);
}

// Round 5
// 87.477 us; speedup vs baseline: 1.0125x; 1.0125x over previous
//
#include <hip/hip_runtime.h>

#define OUTS 7
#define CC 256
#define HH 56
#define WW 56
#define PX (HH * WW)   // 3136
#define STRIDE8 57     // uint4 pixels per LDS row (odd: spreads banks)
#define SPLIT 2        // ROI-list split across sibling blocks
#define MAXROI 96

typedef _Float16 half2_t __attribute__((ext_vector_type(2)));  // trivially copyable

__device__ __forceinline__ unsigned packh2(float a, float b) {
    half2_t h = { (_Float16)a, (_Float16)b };
    return __builtin_bit_cast(unsigned, h);
}

// R15: revert to R13 (best measured: 86.32us). R14's exact-bounds scan
// REGRESSED (+2.25us): per-lane-variable loop bounds + tail branch cost
// more in exec-mask divergence than the ~7 duplicate clamped ds_read_b128
// cost in LDS throughput (~12cyc each). The clamped 2x2 chunking below is
// the measured local optimum from both sides (R13 -1.1us vs b64 version;
// R14 +2.25us vs branchier exact version). Session phase ledger: staging
// off critical path at SPLIT<=2 (R11/R12), scan shape optimal (R13/R14),
// remainder = harness fill floor (~44us @ 77% HBM peak) + compulsory
// 25.7MB staging. Pre-commit: if this reproduces ~86-88us -> ROOFLINE.
__global__ __launch_bounds__(256) void roipool_kernel(
    const float* __restrict__ images, const float* __restrict__ rois,
    const int* __restrict__ roi_idx, float* __restrict__ out, int R)
{
    __shared__ __align__(16) uint4 plane[STRIDE8 * HH];  // 51072 B
    __shared__ int    list[MAXROI];
    __shared__ unsigned short ys[MAXROI * 7];   // sy | ey<<8
    __shared__ unsigned short xs[MAXROI * 7];   // sx | ex<<8
    __shared__ int cnt;

    const int b  = blockIdx.x;
    const int s  = b & (SPLIT - 1);
    const int pq = b >> 1;             // n*32 + c-octet
    const int n  = pq >> 5;
    const int c0 = (pq & 31) * 8;
    const int t  = threadIdx.x;

    // Deterministic ascending-r compaction (wave 0 only) -- identical list
    // order across sibling blocks (R4 lesson: atomicAdd order is not).
    if (t < 64) {
        int base = 0;
        #pragma unroll
        for (int k = 0; k < 4; ++k) {
            int r = k * 64 + t;
            bool match = (r < R) && (roi_idx[r] == n);
            unsigned long long mask = __ballot(match);
            int pos = base + __popcll(mask & ((1ULL << t) - 1ULL));
            if (match && pos < MAXROI) list[pos] = r;
            base += __popcll(mask);
        }
        if (t == 0) cnt = (base < MAXROI) ? base : MAXROI;
    }

    // Stage 8 planes packed-fp16: plane[y*57+x] = {h2(c0,c1),h2(c2,c3),
    // h2(c4,c5),h2(c6,c7)}. 784 pixel-quads, 14 quads/row -> no row spans.
    const float* base8 = images + (size_t)(n * CC + c0) * PX;
    #pragma unroll
    for (int k = 0; k < 4; ++k) {
        int idx = t + k * 256;
        if (idx < PX / 4) {
            float4 v[8];
            #pragma unroll
            for (int p = 0; p < 8; ++p)
                v[p] = reinterpret_cast<const float4*>(base8 + (size_t)p * PX)[idx];
            int y  = idx / 14;
            int x0 = (idx - y * 14) * 4;
            uint4* dst = &plane[y * STRIDE8 + x0];
            #pragma unroll
            for (int q = 0; q < 4; ++q) {
                const float f0 = ((const float*)&v[0])[q];
                const float f1 = ((const float*)&v[1])[q];
                const float f2 = ((const float*)&v[2])[q];
                const float f3 = ((const float*)&v[3])[q];
                const float f4 = ((const float*)&v[4])[q];
                const float f5 = ((const float*)&v[5])[q];
                const float f6 = ((const float*)&v[6])[q];
                const float f7 = ((const float*)&v[7])[q];
                dst[q] = make_uint4(packh2(f0, f1), packh2(f2, f3),
                                    packh2(f4, f5), packh2(f6, f7));
            }
        }
    }
    __syncthreads();   // covers list/cnt too

    const int count = cnt;

    // Per-ROI bin-edge tables (e = m*7 + i serves rows and cols).
    for (int e = t; e < count * 7; e += 256) {
        int m = e / 7, i = e - m * 7;
        int r = list[m];
        float4 rv = reinterpret_cast<const float4*>(rois)[r];
        int x1 = (int)floorf(rv.x * (float)WW);
        int y1 = (int)floorf(rv.y * (float)HH);
        int x2 = (int)ceilf (rv.z * (float)WW);
        int y2 = (int)ceilf (rv.w * (float)HH);
        int Hr = y2 - y1, Wr = x2 - x1;
        int sy = y1 + (i * Hr) / 7, ey = y1 + ((i + 1) * Hr + 6) / 7;
        int sx = x1 + (i * Wr) / 7, ex = x1 + ((i + 1) * Wr + 6) / 7;
        ys[m * 7 + i] = (unsigned short)(sy | (ey << 8));
        xs[m * 7 + i] = (unsigned short)(sx | (ex << 8));
    }
    __syncthreads();

    const int wv   = t >> 6;
    const int lane = t & 63;
    const int i = lane / 7;
    const int j = lane - i * 7;

    if (lane < OUTS * OUTS) {
        const half2_t NEG = { (_Float16)-65504.0f, (_Float16)-65504.0f };
        // (chunk s, wave wv) takes list positions m % 8 == s + 2*wv.
        for (int m = (wv << 1) + s; m < count; m += SPLIT * 4) {
            int r = list[m];
            int yse = ys[m * 7 + i];
            int xse = xs[m * 7 + j];
            int sy = yse & 255, ey = yse >> 8;
            int sx = xse & 255, ex = xse >> 8;

            half2_t a01 = NEG, a23 = NEG, a45 = NEG, a67 = NEG;

            // 2-row x 2-col clamped steps: 4 independent ds_read_b128 per
            // step (ILP); duplicate clamped reads are identity under max.
            for (int y = sy; y < ey; y += 2) {
                const uint4* r0 = plane + y * STRIDE8;
                const uint4* r1 = plane + min(y + 1, ey - 1) * STRIDE8;
                for (int x = sx; x < ex; x += 2) {
                    int xb = min(x + 1, ex - 1);
                    uint4 v0 = r0[x], v1 = r0[xb];
                    uint4 w0 = r1[x], w1 = r1[xb];
                    a01 = __builtin_elementwise_max(a01, __builtin_bit_cast(half2_t, v0.x));
                    a23 = __builtin_elementwise_max(a23, __builtin_bit_cast(half2_t, v0.y));
                    a45 = __builtin_elementwise_max(a45, __builtin_bit_cast(half2_t, v0.z));
                    a67 = __builtin_elementwise_max(a67, __builtin_bit_cast(half2_t, v0.w));
                    a01 = __builtin_elementwise_max(a01, __builtin_bit_cast(half2_t, v1.x));
                    a23 = __builtin_elementwise_max(a23, __builtin_bit_cast(half2_t, v1.y));
                    a45 = __builtin_elementwise_max(a45, __builtin_bit_cast(half2_t, v1.z));
                    a67 = __builtin_elementwise_max(a67, __builtin_bit_cast(half2_t, v1.w));
                    a01 = __builtin_elementwise_max(a01, __builtin_bit_cast(half2_t, w0.x));
                    a23 = __builtin_elementwise_max(a23, __builtin_bit_cast(half2_t, w0.y));
                    a45 = __builtin_elementwise_max(a45, __builtin_bit_cast(half2_t, w0.z));
                    a67 = __builtin_elementwise_max(a67, __builtin_bit_cast(half2_t, w0.w));
                    a01 = __builtin_elementwise_max(a01, __builtin_bit_cast(half2_t, w1.x));
                    a23 = __builtin_elementwise_max(a23, __builtin_bit_cast(half2_t, w1.y));
                    a45 = __builtin_elementwise_max(a45, __builtin_bit_cast(half2_t, w1.z));
                    a67 = __builtin_elementwise_max(a67, __builtin_bit_cast(half2_t, w1.w));
                }
            }

            // Unpack fp16 -> f32. Degenerate bins (Wr*Hr==0 edge case) get
            // exact finfo(f32).min to match the reference.
            bool ok = (ey > sy) && (ex > sx);
            const float NF = -3.402823466e+38f;
            float f0 = ok ? (float)a01.x : NF;
            float f1 = ok ? (float)a01.y : NF;
            float f2 = ok ? (float)a23.x : NF;
            float f3 = ok ? (float)a23.y : NF;
            float f4 = ok ? (float)a45.x : NF;
            float f5 = ok ? (float)a45.y : NF;
            float f6 = ok ? (float)a67.x : NF;
            float f7 = ok ? (float)a67.y : NF;

            size_t o = ((size_t)r * CC + c0) * (OUTS * OUTS) + lane;
            out[o]            = f0;
            out[o + 49]       = f1;
            out[o + 49 * 2]   = f2;
            out[o + 49 * 3]   = f3;
            out[o + 49 * 4]   = f4;
            out[o + 49 * 5]   = f5;
            out[o + 49 * 6]   = f6;
            out[o + 49 * 7]   = f7;
        }
    }
}

extern "C" void kernel_launch(void* const* d_in, const int* in_sizes, int n_in,
                              void* d_out, int out_size, void* d_ws, size_t ws_size,
                              hipStream_t stream) {
    const float* images  = (const float*)d_in[0];
    const float* rois    = (const float*)d_in[1];
    const int*   roi_idx = (const int*)d_in[2];
    float* out = (float*)d_out;

    int R = in_sizes[2];                         // 256
    int N = in_sizes[0] / (CC * PX);             // 8

    int grid = N * (CC / 8) * SPLIT;             // 512 blocks
    roipool_kernel<<<grid, 256, 0, stream>>>(images, rois, roi_idx, out, R);
}